// Round 14
// baseline (135.726 us; speedup 1.0000x reference)
//
#include <hip/hip_runtime.h>

#define T 512
#define B 2
#define NH 16
#define FD 16
#define HD 64
#define DP 160
#define CH 64
#define NC 8

typedef __attribute__((ext_vector_type(4))) short short4v;
typedef __attribute__((ext_vector_type(8))) short bf16x8;
typedef __attribute__((ext_vector_type(4))) float f32x4;

__constant__ unsigned char c_iu[120] = {
0,0,0,0,0,0,0,0,0,0,0,0,0,0,0,
1,1,1,1,1,1,1,1,1,1,1,1,1,1,
2,2,2,2,2,2,2,2,2,2,2,2,2,
3,3,3,3,3,3,3,3,3,3,3,3,
4,4,4,4,4,4,4,4,4,4,4,
5,5,5,5,5,5,5,5,5,5,
6,6,6,6,6,6,6,6,6,
7,7,7,7,7,7,7,7,
8,8,8,8,8,8,8,
9,9,9,9,9,9,
10,10,10,10,10,
11,11,11,11,
12,12,12,
13,13,
14};
__constant__ unsigned char c_ju[120] = {
1,2,3,4,5,6,7,8,9,10,11,12,13,14,15,
2,3,4,5,6,7,8,9,10,11,12,13,14,15,
3,4,5,6,7,8,9,10,11,12,13,14,15,
4,5,6,7,8,9,10,11,12,13,14,15,
5,6,7,8,9,10,11,12,13,14,15,
6,7,8,9,10,11,12,13,14,15,
7,8,9,10,11,12,13,14,15,
8,9,10,11,12,13,14,15,
9,10,11,12,13,14,15,
10,11,12,13,14,15,
11,12,13,14,15,
12,13,14,15,
13,14,15,
14,15,
15};

__device__ inline unsigned short f2bf_rne(float x) {
    unsigned u = __float_as_uint(x);
    u += 0x7fff + ((u >> 16) & 1);
    return (unsigned short)(u >> 16);
}
__device__ inline float bf2f(unsigned short h) {
    return __uint_as_float(((unsigned)h) << 16);
}
__device__ inline f32x4 mfma1(bf16x8 a, bf16x8 b, f32x4 acc) {
    return __builtin_amdgcn_mfma_f32_16x16x32_bf16(a, b, acc, 0, 0, 0);
}
__device__ inline bf16x8 hi8(const float4 x, const float4 y) {
    float f[8] = {x.x, x.y, x.z, x.w, y.x, y.y, y.z, y.w};
    bf16x8 r;
    #pragma unroll
    for (int e = 0; e < 8; ++e) r[e] = (short)f2bf_rne(f[e]);
    return r;
}

// row-major features
__device__ inline void feat40(const float* __restrict__ x, int q4,
                              unsigned short* __restrict__ dst) {
    #pragma unroll
    for (int g = 0; g < 10; ++g) {
        short4v s;
        #pragma unroll
        for (int e = 0; e < 4; ++e) {
            const int D = q4 * 40 + g * 4 + e;
            float f;
            if (D == 0)       f = 1.f;
            else if (D < 17)  f = x[D-1] * 0.5f;
            else if (D < 33)  { float a = x[D-17]; f = a * a * 0.17677669529663687f; }
            else if (D < 153) { int p = D - 33; f = x[c_iu[p]] * x[c_ju[p]] * 0.25f; }
            else              f = 0.f;
            s[e] = (short)f2bf_rne(f);
        }
        *(short4v*)(dst + q4 * 40 + g * 4) = s;
    }
}

// transposed features
__device__ inline void feat40T(const float* __restrict__ x, int q4, int r,
                               unsigned short (*KT)[72]) {
    #pragma unroll
    for (int g = 0; g < 10; ++g) {
        #pragma unroll
        for (int e = 0; e < 4; ++e) {
            const int D = q4 * 40 + g * 4 + e;
            float f;
            if (D == 0)       f = 1.f;
            else if (D < 17)  f = x[D-1] * 0.5f;
            else if (D < 33)  { float a = x[D-17]; f = a * a * 0.17677669529663687f; }
            else if (D < 153) { int p = D - 33; f = x[c_iu[p]] * x[c_ju[p]] * 0.25f; }
            else              f = 0.f;
            KT[D][r] = f2bf_rne(f);
        }
    }
}

// ---- 1) proj: Cp(bf16) = hs @ [Wq|Wk|Wv]^T; fp32 in, convert-in-staging,
//      64x96 tile, BK=64, dbuf (24 MFMA/iter shadow covers ~50 cyc cvt) ----
__global__ __launch_bounds__(256)
void gemm_proj(const float* __restrict__ hs, const float* __restrict__ Wq,
               const float* __restrict__ Wk, const float* __restrict__ Wv,
               short* __restrict__ C) {
    __shared__ short sA[2][64][72], sB[2][96][72];  // 46 KB
    const int tid = threadIdx.x;
    const int bm = blockIdx.y * 64, bn = blockIdx.x * 96;
    const int lane = tid & 63, w = tid >> 6;
    const int wm = (w & 1) * 32, wn = (w >> 1) * 48;
    const int srA = tid >> 2, skA = (tid & 3) * 16;
    const int srB = tid >> 1, skB = (tid & 1) * 32;
    const int fm = lane & 15, fk = (lane >> 4) * 8;
    f32x4 acc[2][3] = {};
    const float* pA = hs + (size_t)(bm + srA) * 1024 + skA;
    const float* pB = nullptr;
    if (tid < 192) {
        const int row = bn + srB;
        pB = (row < 256)  ? Wq + (size_t)row * 1024
           : (row < 512)  ? Wk + (size_t)(row - 256) * 1024
                          : Wv + (size_t)(row - 512) * 1024;
        pB += skB;
    }
    float4 a0 = *(const float4*)pA,        a1 = *(const float4*)(pA + 4);
    float4 a2 = *(const float4*)(pA + 8),  a3 = *(const float4*)(pA + 12);
    float4 b0, b1, b2, b3, b4, b5, b6, b7;
    if (tid < 192) {
        b0 = *(const float4*)pB;        b1 = *(const float4*)(pB + 4);
        b2 = *(const float4*)(pB + 8);  b3 = *(const float4*)(pB + 12);
        b4 = *(const float4*)(pB + 16); b5 = *(const float4*)(pB + 20);
        b6 = *(const float4*)(pB + 24); b7 = *(const float4*)(pB + 28);
    }
    *(bf16x8*)&sA[0][srA][skA]     = hi8(a0, a1);
    *(bf16x8*)&sA[0][srA][skA + 8] = hi8(a2, a3);
    if (tid < 192) {
        *(bf16x8*)&sB[0][srB][skB]      = hi8(b0, b1);
        *(bf16x8*)&sB[0][srB][skB + 8]  = hi8(b2, b3);
        *(bf16x8*)&sB[0][srB][skB + 16] = hi8(b4, b5);
        *(bf16x8*)&sB[0][srB][skB + 24] = hi8(b6, b7);
    }
    a0 = *(const float4*)(pA + 64); a1 = *(const float4*)(pA + 68);
    a2 = *(const float4*)(pA + 72); a3 = *(const float4*)(pA + 76);
    if (tid < 192) {
        b0 = *(const float4*)(pB + 64); b1 = *(const float4*)(pB + 68);
        b2 = *(const float4*)(pB + 72); b3 = *(const float4*)(pB + 76);
        b4 = *(const float4*)(pB + 80); b5 = *(const float4*)(pB + 84);
        b6 = *(const float4*)(pB + 88); b7 = *(const float4*)(pB + 92);
    }
    __syncthreads();
    for (int k0 = 0; k0 < 1024; k0 += 64) {
        const int bb = (k0 >> 6) & 1;
        bf16x8 a[2][2], bfr[2][3];
        #pragma unroll
        for (int ks = 0; ks < 2; ++ks) {
            #pragma unroll
            for (int i = 0; i < 2; ++i)
                a[ks][i] = *(const bf16x8*)&sA[bb][wm + i*16 + fm][ks*32 + fk];
            #pragma unroll
            for (int j = 0; j < 3; ++j)
                bfr[ks][j] = *(const bf16x8*)&sB[bb][wn + j*16 + fm][ks*32 + fk];
        }
        if (k0 + 64 < 1024) {
            *(bf16x8*)&sA[bb^1][srA][skA]     = hi8(a0, a1);
            *(bf16x8*)&sA[bb^1][srA][skA + 8] = hi8(a2, a3);
            if (tid < 192) {
                *(bf16x8*)&sB[bb^1][srB][skB]      = hi8(b0, b1);
                *(bf16x8*)&sB[bb^1][srB][skB + 8]  = hi8(b2, b3);
                *(bf16x8*)&sB[bb^1][srB][skB + 16] = hi8(b4, b5);
                *(bf16x8*)&sB[bb^1][srB][skB + 24] = hi8(b6, b7);
            }
        }
        if (k0 + 128 < 1024) {
            a0 = *(const float4*)(pA + k0 + 128); a1 = *(const float4*)(pA + k0 + 132);
            a2 = *(const float4*)(pA + k0 + 136); a3 = *(const float4*)(pA + k0 + 140);
            if (tid < 192) {
                b0 = *(const float4*)(pB + k0 + 128); b1 = *(const float4*)(pB + k0 + 132);
                b2 = *(const float4*)(pB + k0 + 136); b3 = *(const float4*)(pB + k0 + 140);
                b4 = *(const float4*)(pB + k0 + 144); b5 = *(const float4*)(pB + k0 + 148);
                b6 = *(const float4*)(pB + k0 + 152); b7 = *(const float4*)(pB + k0 + 156);
            }
        }
        #pragma unroll
        for (int ks = 0; ks < 2; ++ks)
            #pragma unroll
            for (int j = 0; j < 3; ++j)
                #pragma unroll
                for (int i = 0; i < 2; ++i)
                    acc[i][j] = mfma1(a[ks][i], bfr[ks][j], acc[i][j]);
        __syncthreads();
    }
    const int crow0 = (lane >> 4) * 4, ccol = lane & 15;
    #pragma unroll
    for (int i = 0; i < 2; ++i)
        #pragma unroll
        for (int j = 0; j < 3; ++j)
            #pragma unroll
            for (int r = 0; r < 4; ++r)
                C[(size_t)(bm + wm + i*16 + crow0 + r) * 1536 + bn + wn + j*16 + ccol] =
                    (short)f2bf_rne(acc[i][j][r]);
}

// ---- 2) chunk_state: Cp bf16 in ----
__global__ __launch_bounds__(256)
void chunk_state(const short* __restrict__ Cp, short* __restrict__ S, float* __restrict__ Z) {
    const int bh = blockIdx.x >> 3, c = blockIdx.x & 7;
    const int b = bh >> 4, h = bh & 15;
    const int tid = threadIdx.x;
    const int lane = tid & 63, w = tid >> 6;
    const int wm = (w & 1) * 32, wn = (w >> 1) * 80;
    const int fm = lane & 15, fk = (lane >> 4) * 8;
    __shared__ __align__(16) float sKP[64][17];
    __shared__ __align__(16) unsigned short sKT[160][72];
    __shared__ __align__(16) unsigned short sVT[64][72];
    const int r = tid >> 2, q4 = tid & 3;
    const size_t rowbase = (size_t)(b*T + c*CH + r) * 1536;
    {
        short4v kv = *(const short4v*)(Cp + rowbase + 256 + h*16 + q4*4);
        float4 kf;
        kf.x = bf2f((unsigned short)kv[0]); kf.y = bf2f((unsigned short)kv[1]);
        kf.z = bf2f((unsigned short)kv[2]); kf.w = bf2f((unsigned short)kv[3]);
        *(float4*)&sKP[r][q4*4] = kf;
    }
    {
        const short* vsrc = Cp + rowbase + 512 + h*HD + q4*16;
        bf16x8 v0 = *(const bf16x8*)vsrc, v1 = *(const bf16x8*)(vsrc + 8);
        #pragma unroll
        for (int e = 0; e < 8; ++e) {
            sVT[q4*16 + e][r]     = (unsigned short)v0[e];
            sVT[q4*16 + 8 + e][r] = (unsigned short)v1[e];
        }
    }
    __syncthreads();
    feat40T(sKP[r], q4, r, sKT);
    __syncthreads();
    if (tid < DP) {
        float zz = 0.f;
        #pragma unroll
        for (int blk = 0; blk < 8; ++blk) {
            bf16x8 v = *(const bf16x8*)&sKT[tid][blk*8];
            #pragma unroll
            for (int e = 0; e < 8; ++e) zz += bf2f((unsigned short)v[e]);
        }
        Z[((size_t)(bh*NC + c)) * DP + tid] = zz;
    }
    f32x4 acc[2][5] = {};
    #pragma unroll
    for (int k0 = 0; k0 < 64; k0 += 32) {
        bf16x8 a[2];
        #pragma unroll
        for (int i = 0; i < 2; ++i)
            a[i] = *(const bf16x8*)&sVT[wm + i*16 + fm][k0 + fk];
        #pragma unroll
        for (int j = 0; j < 5; ++j) {
            bf16x8 bv = *(const bf16x8*)&sKT[wn + j*16 + fm][k0 + fk];
            #pragma unroll
            for (int i = 0; i < 2; ++i)
                acc[i][j] = mfma1(a[i], bv, acc[i][j]);
        }
    }
    const int crow0 = (lane >> 4) * 4, ccol = lane & 15;
    short* Sb = S + ((size_t)(bh*NC + c)) * CH * DP;
    #pragma unroll
    for (int i = 0; i < 2; ++i)
        #pragma unroll
        for (int j = 0; j < 5; ++j)
            #pragma unroll
            for (int rr = 0; rr < 4; ++rr)
                Sb[(size_t)(wm + i*16 + crow0 + rr) * DP + wn + j*16 + ccol] =
                    (short)f2bf_rne(acc[i][j][rr]);
}

// ---- 3) chunk_out: Cp bf16 in ----
__global__ __launch_bounds__(256)
void chunk_out(const short* __restrict__ Cp, const short* __restrict__ S,
               const float* __restrict__ Z, short* __restrict__ Y) {
    const int bh = blockIdx.x >> 3, c = blockIdx.x & 7;
    const int b = bh >> 4, h = bh & 15;
    const int tid = threadIdx.x;
    const int lane = tid & 63, w = tid >> 6;
    const int wm = (w & 1) * 32, wn = (w >> 1) * 32;
    const int fm = lane & 15, fk = (lane >> 4) * 8;
    __shared__ __align__(16) float sQP[64][17], sKP[64][17];
    __shared__ __align__(16) unsigned short sQf[64][168], sKf[64][168], sPb[64][168];
    __shared__ __align__(16) unsigned short sAb[64][72];
    __shared__ __align__(16) unsigned short sVT[64][72];
    __shared__ float sZp[DP];
    __shared__ float sDen[64];
    const int r = tid >> 2, q4 = tid & 3;
    const size_t rowbase = (size_t)(b*T + c*CH + r) * 1536;
    {
        short4v qv = *(const short4v*)(Cp + rowbase + h*16 + q4*4);
        short4v kv = *(const short4v*)(Cp + rowbase + 256 + h*16 + q4*4);
        float4 qf, kf;
        qf.x = bf2f((unsigned short)qv[0]); qf.y = bf2f((unsigned short)qv[1]);
        qf.z = bf2f((unsigned short)qv[2]); qf.w = bf2f((unsigned short)qv[3]);
        kf.x = bf2f((unsigned short)kv[0]); kf.y = bf2f((unsigned short)kv[1]);
        kf.z = bf2f((unsigned short)kv[2]); kf.w = bf2f((unsigned short)kv[3]);
        *(float4*)&sQP[r][q4*4] = qf;
        *(float4*)&sKP[r][q4*4] = kf;
    }
    {
        const short* vsrc = Cp + rowbase + 512 + h*HD + q4*16;
        bf16x8 v0 = *(const bf16x8*)vsrc, v1 = *(const bf16x8*)(vsrc + 8);
        #pragma unroll
        for (int e = 0; e < 8; ++e) {
            sVT[q4*16 + e][r]     = (unsigned short)v0[e];
            sVT[q4*16 + 8 + e][r] = (unsigned short)v1[e];
        }
    }
    if (tid < DP) {
        float zz = 0.f;
        for (int cc = 0; cc < c; ++cc) zz += Z[((size_t)(bh*NC + cc)) * DP + tid];
        sZp[tid] = zz;
    }
    __syncthreads();
    feat40(sQP[r], q4, (unsigned short*)sQf[r]);
    feat40(sKP[r], q4, (unsigned short*)sKf[r]);
    for (int e = tid; e < 1280; e += 256) {
        const int d = e / 20, D8 = (e % 20) * 8;
        float a[8] = {};
        for (int cc = 0; cc < c; ++cc) {
            bf16x8 s = *(const bf16x8*)(S + (((size_t)(bh*NC + cc)) * CH + d) * DP + D8);
            #pragma unroll
            for (int e2 = 0; e2 < 8; ++e2) a[e2] += bf2f((unsigned short)s[e2]);
        }
        bf16x8 o;
        #pragma unroll
        for (int e2 = 0; e2 < 8; ++e2) o[e2] = (short)f2bf_rne(a[e2]);
        *(bf16x8*)&sPb[d][D8] = o;
    }
    __syncthreads();
    f32x4 accA[2][2] = {};
    f32x4 accI[2][2] = {};
    for (int k0 = 0; k0 < DP; k0 += 32) {
        bf16x8 qv[2];
        #pragma unroll
        for (int i = 0; i < 2; ++i)
            qv[i] = *(const bf16x8*)&sQf[wm + i*16 + fm][k0 + fk];
        #pragma unroll
        for (int j = 0; j < 2; ++j) {
            bf16x8 kv = *(const bf16x8*)&sKf[wn + j*16 + fm][k0 + fk];
            bf16x8 pv = *(const bf16x8*)&sPb[wn + j*16 + fm][k0 + fk];
            #pragma unroll
            for (int i = 0; i < 2; ++i) {
                accA[i][j] = mfma1(qv[i], kv, accA[i][j]);
                accI[i][j] = mfma1(qv[i], pv, accI[i][j]);
            }
        }
    }
    {
        float dp = 0.f;
        #pragma unroll
        for (int g = 0; g < 5; ++g) {
            bf16x8 v = *(const bf16x8*)&sQf[r][q4*40 + g*8];
            #pragma unroll
            for (int e = 0; e < 8; ++e)
                dp += bf2f((unsigned short)v[e]) * sZp[q4*40 + g*8 + e];
        }
        dp += __shfl_xor(dp, 1);
        dp += __shfl_xor(dp, 2);
        if (q4 == 0) sDen[r] = dp;
    }
    const int crow0 = (lane >> 4) * 4, ccol = lane & 15;
    #pragma unroll
    for (int i = 0; i < 2; ++i)
        #pragma unroll
        for (int j = 0; j < 2; ++j)
            #pragma unroll
            for (int rr = 0; rr < 4; ++rr) {
                const int t_ = wm + i*16 + crow0 + rr, s_ = wn + j*16 + ccol;
                sAb[t_][s_] = (s_ <= t_) ? f2bf_rne(accA[i][j][rr]) : 0;
            }
    __syncthreads();
    {
        float rs = 0.f;
        bf16x8 v0 = *(const bf16x8*)&sAb[r][q4*16];
        bf16x8 v1 = *(const bf16x8*)&sAb[r][q4*16 + 8];
        #pragma unroll
        for (int e = 0; e < 8; ++e)
            rs += bf2f((unsigned short)v0[e]) + bf2f((unsigned short)v1[e]);
        rs += __shfl_xor(rs, 1);
        rs += __shfl_xor(rs, 2);
        if (q4 == 0) sDen[r] += rs;
    }
    __syncthreads();
    #pragma unroll
    for (int k0 = 0; k0 < 64; k0 += 32) {
        bf16x8 a[2];
        #pragma unroll
        for (int i = 0; i < 2; ++i)
            a[i] = *(const bf16x8*)&sAb[wm + i*16 + fm][k0 + fk];
        #pragma unroll
        for (int j = 0; j < 2; ++j) {
            bf16x8 bv = *(const bf16x8*)&sVT[wn + j*16 + fm][k0 + fk];
            #pragma unroll
            for (int i = 0; i < 2; ++i)
                accI[i][j] = mfma1(a[i], bv, accI[i][j]);
        }
    }
    #pragma unroll
    for (int i = 0; i < 2; ++i)
        #pragma unroll
        for (int rr = 0; rr < 4; ++rr) {
            const int t_ = wm + i*16 + crow0 + rr;
            const float inv = 1.f / (sDen[t_] + 1e-12f);
            const size_t grow = (size_t)(b*T + c*CH + t_) * 1024 + h*HD;
            #pragma unroll
            for (int j = 0; j < 2; ++j)
                Y[grow + wn + j*16 + ccol] = (short)f2bf_rne(accI[i][j][rr] * inv);
        }
}

// ---- 4) out: out = Y @ Wo^T; Wo fp32 convert-in-staging, 64x64, BK=64, dbuf ----
__global__ __launch_bounds__(256)
void gemm_out(const short* __restrict__ A, const float* __restrict__ Wo,
              float* __restrict__ C) {
    __shared__ short sA[2][64][72], sB[2][64][72];  // 36.9 KB
    const int tid = threadIdx.x;
    const int bm = blockIdx.y * 64, bn = blockIdx.x * 64;
    const int lane = tid & 63, w = tid >> 6;
    const int wm = (w & 1) * 32, wn = (w >> 1) * 32;
    const int srow = tid >> 2, skq = (tid & 3) * 16;
    const int fm = lane & 15, fk = (lane >> 4) * 8;
    f32x4 acc[2][2] = {};
    const short* pA = A  + (size_t)(bm + srow) * 1024 + skq;
    const float* pB = Wo + (size_t)(bn + srow) * 1024 + skq;
    bf16x8 va0 = *(const bf16x8*)pA, va1 = *(const bf16x8*)(pA + 8);
    float4 b0 = *(const float4*)pB,       b1 = *(const float4*)(pB + 4);
    float4 b2 = *(const float4*)(pB + 8), b3 = *(const float4*)(pB + 12);
    *(bf16x8*)&sA[0][srow][skq]     = va0;
    *(bf16x8*)&sA[0][srow][skq + 8] = va1;
    *(bf16x8*)&sB[0][srow][skq]     = hi8(b0, b1);
    *(bf16x8*)&sB[0][srow][skq + 8] = hi8(b2, b3);
    va0 = *(const bf16x8*)(pA + 64); va1 = *(const bf16x8*)(pA + 72);
    b0 = *(const float4*)(pB + 64); b1 = *(const float4*)(pB + 68);
    b2 = *(const float4*)(pB + 72); b3 = *(const float4*)(pB + 76);
    __syncthreads();
    for (int k0 = 0; k0 < 1024; k0 += 64) {
        const int bb = (k0 >> 6) & 1;
        bf16x8 a[2][2], b2f[2][2];
        #pragma unroll
        for (int ks = 0; ks < 2; ++ks)
            #pragma unroll
            for (int i = 0; i < 2; ++i) {
                a[ks][i]   = *(const bf16x8*)&sA[bb][wm + i*16 + fm][ks*32 + fk];
                b2f[ks][i] = *(const bf16x8*)&sB[bb][wn + i*16 + fm][ks*32 + fk];
            }
        if (k0 + 64 < 1024) {
            *(bf16x8*)&sA[bb^1][srow][skq]     = va0;
            *(bf16x8*)&sA[bb^1][srow][skq + 8] = va1;
            *(bf16x8*)&sB[bb^1][srow][skq]     = hi8(b0, b1);
            *(bf16x8*)&sB[bb^1][srow][skq + 8] = hi8(b2, b3);
        }
        if (k0 + 128 < 1024) {
            va0 = *(const bf16x8*)(pA + k0 + 128); va1 = *(const bf16x8*)(pA + k0 + 136);
            b0 = *(const float4*)(pB + k0 + 128); b1 = *(const float4*)(pB + k0 + 132);
            b2 = *(const float4*)(pB + k0 + 136); b3 = *(const float4*)(pB + k0 + 140);
        }
        #pragma unroll
        for (int ks = 0; ks < 2; ++ks)
            #pragma unroll
            for (int i = 0; i < 2; ++i)
                #pragma unroll
                for (int j = 0; j < 2; ++j)
                    acc[i][j] = mfma1(a[ks][i], b2f[ks][j], acc[i][j]);
        __syncthreads();
    }
    const int crow0 = (lane >> 4) * 4, ccol = lane & 15;
    #pragma unroll
    for (int i = 0; i < 2; ++i)
        #pragma unroll
        for (int j = 0; j < 2; ++j)
            #pragma unroll
            for (int r = 0; r < 4; ++r)
                C[(size_t)(bm + wm + i*16 + crow0 + r) * 1024 + bn + wn + j*16 + ccol] = acc[i][j][r];
}

extern "C" void kernel_launch(void* const* d_in, const int* in_sizes, int n_in,
                              void* d_out, int out_size, void* d_ws, size_t ws_size,
                              hipStream_t stream) {
    const float* hs = (const float*)d_in[0];
    const float* Wq = (const float*)d_in[1];
    const float* Wk = (const float*)d_in[2];
    const float* Wv = (const float*)d_in[3];
    const float* Wo = (const float*)d_in[4];
    float* out = (float*)d_out;

    char* p = (char*)d_ws;
    short* Cp = (short*)p; p += (size_t)1024*1536*2;
    short* S  = (short*)p; p += (size_t)32*NC*CH*DP*2;
    float* Z  = (float*)p; p += (size_t)32*NC*DP*4;
    short* Y  = (short*)p; p += (size_t)1048576*2;

    dim3 blk(256);
    gemm_proj<<<dim3(16, 16), blk, 0, stream>>>(hs, Wq, Wk, Wv, Cp);
    chunk_state<<<dim3(256), blk, 0, stream>>>(Cp, S, Z);
    chunk_out<<<dim3(256), blk, 0, stream>>>(Cp, S, Z, Y);
    gemm_out<<<dim3(16, 16), blk, 0, stream>>>(Y, Wo, out);
}

// Round 15
// 126.709 us; speedup vs baseline: 1.0712x; 1.0712x over previous
//
#include <hip/hip_runtime.h>

#define T 512
#define B 2
#define NH 16
#define FD 16
#define HD 64
#define DP 160
#define CH 64
#define NC 8

typedef __attribute__((ext_vector_type(4))) short short4v;
typedef __attribute__((ext_vector_type(8))) short bf16x8;
typedef __attribute__((ext_vector_type(4))) float f32x4;

__constant__ unsigned char c_iu[120] = {
0,0,0,0,0,0,0,0,0,0,0,0,0,0,0,
1,1,1,1,1,1,1,1,1,1,1,1,1,1,
2,2,2,2,2,2,2,2,2,2,2,2,2,
3,3,3,3,3,3,3,3,3,3,3,3,
4,4,4,4,4,4,4,4,4,4,4,
5,5,5,5,5,5,5,5,5,5,
6,6,6,6,6,6,6,6,6,
7,7,7,7,7,7,7,7,
8,8,8,8,8,8,8,
9,9,9,9,9,9,
10,10,10,10,10,
11,11,11,11,
12,12,12,
13,13,
14};
__constant__ unsigned char c_ju[120] = {
1,2,3,4,5,6,7,8,9,10,11,12,13,14,15,
2,3,4,5,6,7,8,9,10,11,12,13,14,15,
3,4,5,6,7,8,9,10,11,12,13,14,15,
4,5,6,7,8,9,10,11,12,13,14,15,
5,6,7,8,9,10,11,12,13,14,15,
6,7,8,9,10,11,12,13,14,15,
7,8,9,10,11,12,13,14,15,
8,9,10,11,12,13,14,15,
9,10,11,12,13,14,15,
10,11,12,13,14,15,
11,12,13,14,15,
12,13,14,15,
13,14,15,
14,15,
15};

__device__ inline unsigned short f2bf_rne(float x) {
    unsigned u = __float_as_uint(x);
    u += 0x7fff + ((u >> 16) & 1);
    return (unsigned short)(u >> 16);
}
__device__ inline float bf2f(unsigned short h) {
    return __uint_as_float(((unsigned)h) << 16);
}
__device__ inline f32x4 mfma1(bf16x8 a, bf16x8 b, f32x4 acc) {
    return __builtin_amdgcn_mfma_f32_16x16x32_bf16(a, b, acc, 0, 0, 0);
}

// row-major features
__device__ inline void feat40(const float* __restrict__ x, int q4,
                              unsigned short* __restrict__ dst) {
    #pragma unroll
    for (int g = 0; g < 10; ++g) {
        short4v s;
        #pragma unroll
        for (int e = 0; e < 4; ++e) {
            const int D = q4 * 40 + g * 4 + e;
            float f;
            if (D == 0)       f = 1.f;
            else if (D < 17)  f = x[D-1] * 0.5f;
            else if (D < 33)  { float a = x[D-17]; f = a * a * 0.17677669529663687f; }
            else if (D < 153) { int p = D - 33; f = x[c_iu[p]] * x[c_ju[p]] * 0.25f; }
            else              f = 0.f;
            s[e] = (short)f2bf_rne(f);
        }
        *(short4v*)(dst + q4 * 40 + g * 4) = s;
    }
}

// transposed features
__device__ inline void feat40T(const float* __restrict__ x, int q4, int r,
                               unsigned short (*KT)[72]) {
    #pragma unroll
    for (int g = 0; g < 10; ++g) {
        #pragma unroll
        for (int e = 0; e < 4; ++e) {
            const int D = q4 * 40 + g * 4 + e;
            float f;
            if (D == 0)       f = 1.f;
            else if (D < 17)  f = x[D-1] * 0.5f;
            else if (D < 33)  { float a = x[D-17]; f = a * a * 0.17677669529663687f; }
            else if (D < 153) { int p = D - 33; f = x[c_iu[p]] * x[c_ju[p]] * 0.25f; }
            else              f = 0.f;
            KT[D][r] = f2bf_rne(f);
        }
    }
}

// ---- 1) preconv: everything -> single bf16 plane ----
__global__ __launch_bounds__(256)
void preconv(const float* __restrict__ hs, const float* __restrict__ Wq,
             const float* __restrict__ Wk, const float* __restrict__ Wv,
             const float* __restrict__ Wo,
             short* __restrict__ hsh, short* __restrict__ Wch, short* __restrict__ Woh) {
    const int i4 = blockIdx.x * 256 + threadIdx.x;
    const float* src; short* dh; size_t off4;
    if (i4 < 262144)      { src = hs; dh = hsh;          off4 = i4; }
    else if (i4 < 327680) { src = Wq; dh = Wch;          off4 = i4 - 262144; }
    else if (i4 < 393216) { src = Wk; dh = Wch + 262144; off4 = i4 - 327680; }
    else if (i4 < 655360) { src = Wv; dh = Wch + 524288; off4 = i4 - 393216; }
    else                  { src = Wo; dh = Woh;          off4 = i4 - 655360; }
    float4 v = *(const float4*)(src + off4 * 4);
    float vv[4] = {v.x, v.y, v.z, v.w};
    short4v sh;
    #pragma unroll
    for (int e = 0; e < 4; ++e) sh[e] = (short)f2bf_rne(vv[e]);
    *(short4v*)(dh + off4 * 4) = sh;
}

// ---- 2) proj: Cp(bf16) = hs @ Wc^T; pre-split bf16 in, 64x96, BK=64, dbuf ----
__global__ __launch_bounds__(256)
void gemm_proj(const short* __restrict__ A, const short* __restrict__ Bm,
               short* __restrict__ C) {
    __shared__ short sA[2][64][72], sB[2][96][72];  // 46 KB
    const int tid = threadIdx.x;
    const int bm = blockIdx.y * 64, bn = blockIdx.x * 96;
    const int lane = tid & 63, w = tid >> 6;
    const int wm = (w & 1) * 32, wn = (w >> 1) * 48;
    const int srA = tid >> 2, skA = (tid & 3) * 16;
    const int srB = tid >> 1, skB = (tid & 1) * 32;
    const int fm = lane & 15, fk = (lane >> 4) * 8;
    f32x4 acc[2][3] = {};
    const short* pA = A  + (size_t)(bm + srA) * 1024 + skA;
    const short* pB = Bm + (size_t)(bn + (srB < 96 ? srB : 0)) * 1024 + skB;
    bf16x8 va0 = *(const bf16x8*)pA, va1 = *(const bf16x8*)(pA + 8);
    bf16x8 vb0, vb1, vb2, vb3;
    if (tid < 192) {
        vb0 = *(const bf16x8*)pB;        vb1 = *(const bf16x8*)(pB + 8);
        vb2 = *(const bf16x8*)(pB + 16); vb3 = *(const bf16x8*)(pB + 24);
    }
    *(bf16x8*)&sA[0][srA][skA]     = va0;
    *(bf16x8*)&sA[0][srA][skA + 8] = va1;
    if (tid < 192) {
        *(bf16x8*)&sB[0][srB][skB]      = vb0;
        *(bf16x8*)&sB[0][srB][skB + 8]  = vb1;
        *(bf16x8*)&sB[0][srB][skB + 16] = vb2;
        *(bf16x8*)&sB[0][srB][skB + 24] = vb3;
    }
    va0 = *(const bf16x8*)(pA + 64); va1 = *(const bf16x8*)(pA + 72);
    if (tid < 192) {
        vb0 = *(const bf16x8*)(pB + 64); vb1 = *(const bf16x8*)(pB + 72);
        vb2 = *(const bf16x8*)(pB + 80); vb3 = *(const bf16x8*)(pB + 88);
    }
    __syncthreads();
    for (int k0 = 0; k0 < 1024; k0 += 64) {
        const int bb = (k0 >> 6) & 1;
        bf16x8 a[2][2], bfr[2][3];
        #pragma unroll
        for (int ks = 0; ks < 2; ++ks) {
            #pragma unroll
            for (int i = 0; i < 2; ++i)
                a[ks][i] = *(const bf16x8*)&sA[bb][wm + i*16 + fm][ks*32 + fk];
            #pragma unroll
            for (int j = 0; j < 3; ++j)
                bfr[ks][j] = *(const bf16x8*)&sB[bb][wn + j*16 + fm][ks*32 + fk];
        }
        if (k0 + 64 < 1024) {
            *(bf16x8*)&sA[bb^1][srA][skA]     = va0;
            *(bf16x8*)&sA[bb^1][srA][skA + 8] = va1;
            if (tid < 192) {
                *(bf16x8*)&sB[bb^1][srB][skB]      = vb0;
                *(bf16x8*)&sB[bb^1][srB][skB + 8]  = vb1;
                *(bf16x8*)&sB[bb^1][srB][skB + 16] = vb2;
                *(bf16x8*)&sB[bb^1][srB][skB + 24] = vb3;
            }
        }
        if (k0 + 128 < 1024) {
            va0 = *(const bf16x8*)(pA + k0 + 128); va1 = *(const bf16x8*)(pA + k0 + 136);
            if (tid < 192) {
                vb0 = *(const bf16x8*)(pB + k0 + 128); vb1 = *(const bf16x8*)(pB + k0 + 136);
                vb2 = *(const bf16x8*)(pB + k0 + 144); vb3 = *(const bf16x8*)(pB + k0 + 152);
            }
        }
        #pragma unroll
        for (int ks = 0; ks < 2; ++ks)
            #pragma unroll
            for (int j = 0; j < 3; ++j)
                #pragma unroll
                for (int i = 0; i < 2; ++i)
                    acc[i][j] = mfma1(a[ks][i], bfr[ks][j], acc[i][j]);
        __syncthreads();
    }
    const int crow0 = (lane >> 4) * 4, ccol = lane & 15;
    #pragma unroll
    for (int i = 0; i < 2; ++i)
        #pragma unroll
        for (int j = 0; j < 3; ++j)
            #pragma unroll
            for (int r = 0; r < 4; ++r)
                C[(size_t)(bm + wm + i*16 + crow0 + r) * 1536 + bn + wn + j*16 + ccol] =
                    (short)f2bf_rne(acc[i][j][r]);
}

// ---- 3) chunk_state: Cp bf16 in ----
__global__ __launch_bounds__(256)
void chunk_state(const short* __restrict__ Cp, short* __restrict__ S, float* __restrict__ Z) {
    const int bh = blockIdx.x >> 3, c = blockIdx.x & 7;
    const int b = bh >> 4, h = bh & 15;
    const int tid = threadIdx.x;
    const int lane = tid & 63, w = tid >> 6;
    const int wm = (w & 1) * 32, wn = (w >> 1) * 80;
    const int fm = lane & 15, fk = (lane >> 4) * 8;
    __shared__ __align__(16) float sKP[64][17];
    __shared__ __align__(16) unsigned short sKT[160][72];
    __shared__ __align__(16) unsigned short sVT[64][72];
    const int r = tid >> 2, q4 = tid & 3;
    const size_t rowbase = (size_t)(b*T + c*CH + r) * 1536;
    {
        short4v kv = *(const short4v*)(Cp + rowbase + 256 + h*16 + q4*4);
        float4 kf;
        kf.x = bf2f((unsigned short)kv[0]); kf.y = bf2f((unsigned short)kv[1]);
        kf.z = bf2f((unsigned short)kv[2]); kf.w = bf2f((unsigned short)kv[3]);
        *(float4*)&sKP[r][q4*4] = kf;
    }
    {
        const short* vsrc = Cp + rowbase + 512 + h*HD + q4*16;
        bf16x8 v0 = *(const bf16x8*)vsrc, v1 = *(const bf16x8*)(vsrc + 8);
        #pragma unroll
        for (int e = 0; e < 8; ++e) {
            sVT[q4*16 + e][r]     = (unsigned short)v0[e];
            sVT[q4*16 + 8 + e][r] = (unsigned short)v1[e];
        }
    }
    __syncthreads();
    feat40T(sKP[r], q4, r, sKT);
    __syncthreads();
    if (tid < DP) {
        float zz = 0.f;
        #pragma unroll
        for (int blk = 0; blk < 8; ++blk) {
            bf16x8 v = *(const bf16x8*)&sKT[tid][blk*8];
            #pragma unroll
            for (int e = 0; e < 8; ++e) zz += bf2f((unsigned short)v[e]);
        }
        Z[((size_t)(bh*NC + c)) * DP + tid] = zz;
    }
    f32x4 acc[2][5] = {};
    #pragma unroll
    for (int k0 = 0; k0 < 64; k0 += 32) {
        bf16x8 a[2];
        #pragma unroll
        for (int i = 0; i < 2; ++i)
            a[i] = *(const bf16x8*)&sVT[wm + i*16 + fm][k0 + fk];
        #pragma unroll
        for (int j = 0; j < 5; ++j) {
            bf16x8 bv = *(const bf16x8*)&sKT[wn + j*16 + fm][k0 + fk];
            #pragma unroll
            for (int i = 0; i < 2; ++i)
                acc[i][j] = mfma1(a[i], bv, acc[i][j]);
        }
    }
    const int crow0 = (lane >> 4) * 4, ccol = lane & 15;
    short* Sb = S + ((size_t)(bh*NC + c)) * CH * DP;
    #pragma unroll
    for (int i = 0; i < 2; ++i)
        #pragma unroll
        for (int j = 0; j < 5; ++j)
            #pragma unroll
            for (int rr = 0; rr < 4; ++rr)
                Sb[(size_t)(wm + i*16 + crow0 + rr) * DP + wn + j*16 + ccol] =
                    (short)f2bf_rne(acc[i][j][rr]);
}

// ---- 4) chunk_out: Cp bf16 in ----
__global__ __launch_bounds__(256)
void chunk_out(const short* __restrict__ Cp, const short* __restrict__ S,
               const float* __restrict__ Z, short* __restrict__ Y) {
    const int bh = blockIdx.x >> 3, c = blockIdx.x & 7;
    const int b = bh >> 4, h = bh & 15;
    const int tid = threadIdx.x;
    const int lane = tid & 63, w = tid >> 6;
    const int wm = (w & 1) * 32, wn = (w >> 1) * 32;
    const int fm = lane & 15, fk = (lane >> 4) * 8;
    __shared__ __align__(16) float sQP[64][17], sKP[64][17];
    __shared__ __align__(16) unsigned short sQf[64][168], sKf[64][168], sPb[64][168];
    __shared__ __align__(16) unsigned short sAb[64][72];
    __shared__ __align__(16) unsigned short sVT[64][72];
    __shared__ float sZp[DP];
    __shared__ float sDen[64];
    const int r = tid >> 2, q4 = tid & 3;
    const size_t rowbase = (size_t)(b*T + c*CH + r) * 1536;
    {
        short4v qv = *(const short4v*)(Cp + rowbase + h*16 + q4*4);
        short4v kv = *(const short4v*)(Cp + rowbase + 256 + h*16 + q4*4);
        float4 qf, kf;
        qf.x = bf2f((unsigned short)qv[0]); qf.y = bf2f((unsigned short)qv[1]);
        qf.z = bf2f((unsigned short)qv[2]); qf.w = bf2f((unsigned short)qv[3]);
        kf.x = bf2f((unsigned short)kv[0]); kf.y = bf2f((unsigned short)kv[1]);
        kf.z = bf2f((unsigned short)kv[2]); kf.w = bf2f((unsigned short)kv[3]);
        *(float4*)&sQP[r][q4*4] = qf;
        *(float4*)&sKP[r][q4*4] = kf;
    }
    {
        const short* vsrc = Cp + rowbase + 512 + h*HD + q4*16;
        bf16x8 v0 = *(const bf16x8*)vsrc, v1 = *(const bf16x8*)(vsrc + 8);
        #pragma unroll
        for (int e = 0; e < 8; ++e) {
            sVT[q4*16 + e][r]     = (unsigned short)v0[e];
            sVT[q4*16 + 8 + e][r] = (unsigned short)v1[e];
        }
    }
    if (tid < DP) {
        float zz = 0.f;
        for (int cc = 0; cc < c; ++cc) zz += Z[((size_t)(bh*NC + cc)) * DP + tid];
        sZp[tid] = zz;
    }
    __syncthreads();
    feat40(sQP[r], q4, (unsigned short*)sQf[r]);
    feat40(sKP[r], q4, (unsigned short*)sKf[r]);
    for (int e = tid; e < 1280; e += 256) {
        const int d = e / 20, D8 = (e % 20) * 8;
        float a[8] = {};
        for (int cc = 0; cc < c; ++cc) {
            bf16x8 s = *(const bf16x8*)(S + (((size_t)(bh*NC + cc)) * CH + d) * DP + D8);
            #pragma unroll
            for (int e2 = 0; e2 < 8; ++e2) a[e2] += bf2f((unsigned short)s[e2]);
        }
        bf16x8 o;
        #pragma unroll
        for (int e2 = 0; e2 < 8; ++e2) o[e2] = (short)f2bf_rne(a[e2]);
        *(bf16x8*)&sPb[d][D8] = o;
    }
    __syncthreads();
    f32x4 accA[2][2] = {};
    f32x4 accI[2][2] = {};
    for (int k0 = 0; k0 < DP; k0 += 32) {
        bf16x8 qv[2];
        #pragma unroll
        for (int i = 0; i < 2; ++i)
            qv[i] = *(const bf16x8*)&sQf[wm + i*16 + fm][k0 + fk];
        #pragma unroll
        for (int j = 0; j < 2; ++j) {
            bf16x8 kv = *(const bf16x8*)&sKf[wn + j*16 + fm][k0 + fk];
            bf16x8 pv = *(const bf16x8*)&sPb[wn + j*16 + fm][k0 + fk];
            #pragma unroll
            for (int i = 0; i < 2; ++i) {
                accA[i][j] = mfma1(qv[i], kv, accA[i][j]);
                accI[i][j] = mfma1(qv[i], pv, accI[i][j]);
            }
        }
    }
    {
        float dp = 0.f;
        #pragma unroll
        for (int g = 0; g < 5; ++g) {
            bf16x8 v = *(const bf16x8*)&sQf[r][q4*40 + g*8];
            #pragma unroll
            for (int e = 0; e < 8; ++e)
                dp += bf2f((unsigned short)v[e]) * sZp[q4*40 + g*8 + e];
        }
        dp += __shfl_xor(dp, 1);
        dp += __shfl_xor(dp, 2);
        if (q4 == 0) sDen[r] = dp;
    }
    const int crow0 = (lane >> 4) * 4, ccol = lane & 15;
    #pragma unroll
    for (int i = 0; i < 2; ++i)
        #pragma unroll
        for (int j = 0; j < 2; ++j)
            #pragma unroll
            for (int rr = 0; rr < 4; ++rr) {
                const int t_ = wm + i*16 + crow0 + rr, s_ = wn + j*16 + ccol;
                sAb[t_][s_] = (s_ <= t_) ? f2bf_rne(accA[i][j][rr]) : 0;
            }
    __syncthreads();
    {
        float rs = 0.f;
        bf16x8 v0 = *(const bf16x8*)&sAb[r][q4*16];
        bf16x8 v1 = *(const bf16x8*)&sAb[r][q4*16 + 8];
        #pragma unroll
        for (int e = 0; e < 8; ++e)
            rs += bf2f((unsigned short)v0[e]) + bf2f((unsigned short)v1[e]);
        rs += __shfl_xor(rs, 1);
        rs += __shfl_xor(rs, 2);
        if (q4 == 0) sDen[r] += rs;
    }
    __syncthreads();
    #pragma unroll
    for (int k0 = 0; k0 < 64; k0 += 32) {
        bf16x8 a[2];
        #pragma unroll
        for (int i = 0; i < 2; ++i)
            a[i] = *(const bf16x8*)&sAb[wm + i*16 + fm][k0 + fk];
        #pragma unroll
        for (int j = 0; j < 2; ++j) {
            bf16x8 bv = *(const bf16x8*)&sVT[wn + j*16 + fm][k0 + fk];
            #pragma unroll
            for (int i = 0; i < 2; ++i)
                accI[i][j] = mfma1(a[i], bv, accI[i][j]);
        }
    }
    #pragma unroll
    for (int i = 0; i < 2; ++i)
        #pragma unroll
        for (int rr = 0; rr < 4; ++rr) {
            const int t_ = wm + i*16 + crow0 + rr;
            const float inv = 1.f / (sDen[t_] + 1e-12f);
            const size_t grow = (size_t)(b*T + c*CH + t_) * 1024 + h*HD;
            #pragma unroll
            for (int j = 0; j < 2; ++j)
                Y[grow + wn + j*16 + ccol] = (short)f2bf_rne(accI[i][j][rr] * inv);
        }
}

// ---- 5) out: out = Y @ Woh^T; pre-split bf16, 64x64, BK=64, dbuf ----
__global__ __launch_bounds__(256)
void gemm_out(const short* __restrict__ A, const short* __restrict__ Bm,
              float* __restrict__ C) {
    __shared__ short sA[2][64][72], sB[2][64][72];  // 36.9 KB
    const int tid = threadIdx.x;
    const int bm = blockIdx.y * 64, bn = blockIdx.x * 64;
    const int lane = tid & 63, w = tid >> 6;
    const int wm = (w & 1) * 32, wn = (w >> 1) * 32;
    const int srow = tid >> 2, skq = (tid & 3) * 16;
    const int fm = lane & 15, fk = (lane >> 4) * 8;
    f32x4 acc[2][2] = {};
    const short* pA = A  + (size_t)(bm + srow) * 1024 + skq;
    const short* pB = Bm + (size_t)(bn + srow) * 1024 + skq;
    bf16x8 va0 = *(const bf16x8*)pA, va1 = *(const bf16x8*)(pA + 8);
    bf16x8 vb0 = *(const bf16x8*)pB, vb1 = *(const bf16x8*)(pB + 8);
    *(bf16x8*)&sA[0][srow][skq]     = va0;
    *(bf16x8*)&sA[0][srow][skq + 8] = va1;
    *(bf16x8*)&sB[0][srow][skq]     = vb0;
    *(bf16x8*)&sB[0][srow][skq + 8] = vb1;
    va0 = *(const bf16x8*)(pA + 64); va1 = *(const bf16x8*)(pA + 72);
    vb0 = *(const bf16x8*)(pB + 64); vb1 = *(const bf16x8*)(pB + 72);
    __syncthreads();
    for (int k0 = 0; k0 < 1024; k0 += 64) {
        const int bb = (k0 >> 6) & 1;
        bf16x8 a[2][2], b2[2][2];
        #pragma unroll
        for (int ks = 0; ks < 2; ++ks)
            #pragma unroll
            for (int i = 0; i < 2; ++i) {
                a[ks][i]  = *(const bf16x8*)&sA[bb][wm + i*16 + fm][ks*32 + fk];
                b2[ks][i] = *(const bf16x8*)&sB[bb][wn + i*16 + fm][ks*32 + fk];
            }
        if (k0 + 64 < 1024) {
            *(bf16x8*)&sA[bb^1][srow][skq]     = va0;
            *(bf16x8*)&sA[bb^1][srow][skq + 8] = va1;
            *(bf16x8*)&sB[bb^1][srow][skq]     = vb0;
            *(bf16x8*)&sB[bb^1][srow][skq + 8] = vb1;
        }
        if (k0 + 128 < 1024) {
            va0 = *(const bf16x8*)(pA + k0 + 128); va1 = *(const bf16x8*)(pA + k0 + 136);
            vb0 = *(const bf16x8*)(pB + k0 + 128); vb1 = *(const bf16x8*)(pB + k0 + 136);
        }
        #pragma unroll
        for (int ks = 0; ks < 2; ++ks)
            #pragma unroll
            for (int i = 0; i < 2; ++i)
                #pragma unroll
                for (int j = 0; j < 2; ++j)
                    acc[i][j] = mfma1(a[ks][i], b2[ks][j], acc[i][j]);
        __syncthreads();
    }
    const int crow0 = (lane >> 4) * 4, ccol = lane & 15;
    #pragma unroll
    for (int i = 0; i < 2; ++i)
        #pragma unroll
        for (int j = 0; j < 2; ++j)
            #pragma unroll
            for (int r = 0; r < 4; ++r)
                C[(size_t)(bm + wm + i*16 + crow0 + r) * 1024 + bn + wn + j*16 + ccol] = acc[i][j][r];
}

extern "C" void kernel_launch(void* const* d_in, const int* in_sizes, int n_in,
                              void* d_out, int out_size, void* d_ws, size_t ws_size,
                              hipStream_t stream) {
    const float* hs = (const float*)d_in[0];
    const float* Wq = (const float*)d_in[1];
    const float* Wk = (const float*)d_in[2];
    const float* Wv = (const float*)d_in[3];
    const float* Wo = (const float*)d_in[4];
    float* out = (float*)d_out;

    char* p = (char*)d_ws;
    short* Cp  = (short*)p; p += (size_t)1024*1536*2;
    short* hsh = (short*)p; p += (size_t)1048576*2;
    short* Wch = (short*)p; p += (size_t)1536*1024*2;
    short* Woh = (short*)p; p += (size_t)1048576*2;
    short* S   = (short*)p; p += (size_t)32*NC*CH*DP*2;
    float* Z   = (float*)p; p += (size_t)32*NC*DP*4;
    short* Y   = (short*)p; p += (size_t)1048576*2;

    dim3 blk(256);
    preconv<<<dim3(3584), blk, 0, stream>>>(hs, Wq, Wk, Wv, Wo, hsh, Wch, Woh);
    gemm_proj<<<dim3(16, 16), blk, 0, stream>>>(hsh, Wch, Cp);
    chunk_state<<<dim3(256), blk, 0, stream>>>(Cp, S, Z);
    chunk_out<<<dim3(256), blk, 0, stream>>>(Cp, S, Z, Y);
    gemm_out<<<dim3(16, 16), blk, 0, stream>>>(Y, Woh, out);
}

// Round 16
// 125.250 us; speedup vs baseline: 1.0836x; 1.0116x over previous
//
#include <hip/hip_runtime.h>

#define T 512
#define B 2
#define NH 16
#define FD 16
#define HD 64
#define DP 160
#define CH 64
#define NC 8

typedef __attribute__((ext_vector_type(4))) short short4v;
typedef __attribute__((ext_vector_type(8))) short bf16x8;
typedef __attribute__((ext_vector_type(4))) float f32x4;

__constant__ unsigned char c_iu[120] = {
0,0,0,0,0,0,0,0,0,0,0,0,0,0,0,
1,1,1,1,1,1,1,1,1,1,1,1,1,1,
2,2,2,2,2,2,2,2,2,2,2,2,2,
3,3,3,3,3,3,3,3,3,3,3,3,
4,4,4,4,4,4,4,4,4,4,4,
5,5,5,5,5,5,5,5,5,5,
6,6,6,6,6,6,6,6,6,
7,7,7,7,7,7,7,7,
8,8,8,8,8,8,8,
9,9,9,9,9,9,
10,10,10,10,10,
11,11,11,11,
12,12,12,
13,13,
14};
__constant__ unsigned char c_ju[120] = {
1,2,3,4,5,6,7,8,9,10,11,12,13,14,15,
2,3,4,5,6,7,8,9,10,11,12,13,14,15,
3,4,5,6,7,8,9,10,11,12,13,14,15,
4,5,6,7,8,9,10,11,12,13,14,15,
5,6,7,8,9,10,11,12,13,14,15,
6,7,8,9,10,11,12,13,14,15,
7,8,9,10,11,12,13,14,15,
8,9,10,11,12,13,14,15,
9,10,11,12,13,14,15,
10,11,12,13,14,15,
11,12,13,14,15,
12,13,14,15,
13,14,15,
14,15,
15};

__device__ inline unsigned short f2bf_rne(float x) {
    unsigned u = __float_as_uint(x);
    u += 0x7fff + ((u >> 16) & 1);
    return (unsigned short)(u >> 16);
}
__device__ inline float bf2f(unsigned short h) {
    return __uint_as_float(((unsigned)h) << 16);
}
__device__ inline f32x4 mfma1(bf16x8 a, bf16x8 b, f32x4 acc) {
    return __builtin_amdgcn_mfma_f32_16x16x32_bf16(a, b, acc, 0, 0, 0);
}

// row-major features
__device__ inline void feat40(const float* __restrict__ x, int q4,
                              unsigned short* __restrict__ dst) {
    #pragma unroll
    for (int g = 0; g < 10; ++g) {
        short4v s;
        #pragma unroll
        for (int e = 0; e < 4; ++e) {
            const int D = q4 * 40 + g * 4 + e;
            float f;
            if (D == 0)       f = 1.f;
            else if (D < 17)  f = x[D-1] * 0.5f;
            else if (D < 33)  { float a = x[D-17]; f = a * a * 0.17677669529663687f; }
            else if (D < 153) { int p = D - 33; f = x[c_iu[p]] * x[c_ju[p]] * 0.25f; }
            else              f = 0.f;
            s[e] = (short)f2bf_rne(f);
        }
        *(short4v*)(dst + q4 * 40 + g * 4) = s;
    }
}

// transposed features
__device__ inline void feat40T(const float* __restrict__ x, int q4, int r,
                               unsigned short (*KT)[72]) {
    #pragma unroll
    for (int g = 0; g < 10; ++g) {
        #pragma unroll
        for (int e = 0; e < 4; ++e) {
            const int D = q4 * 40 + g * 4 + e;
            float f;
            if (D == 0)       f = 1.f;
            else if (D < 17)  f = x[D-1] * 0.5f;
            else if (D < 33)  { float a = x[D-17]; f = a * a * 0.17677669529663687f; }
            else if (D < 153) { int p = D - 33; f = x[c_iu[p]] * x[c_ju[p]] * 0.25f; }
            else              f = 0.f;
            KT[D][r] = f2bf_rne(f);
        }
    }
}

// ---- 1) preconv ----
__global__ __launch_bounds__(256)
void preconv(const float* __restrict__ hs, const float* __restrict__ Wq,
             const float* __restrict__ Wk, const float* __restrict__ Wv,
             const float* __restrict__ Wo,
             short* __restrict__ hsh, short* __restrict__ Wch, short* __restrict__ Woh) {
    const int i4 = blockIdx.x * 256 + threadIdx.x;
    const float* src; short* dh; size_t off4;
    if (i4 < 262144)      { src = hs; dh = hsh;          off4 = i4; }
    else if (i4 < 327680) { src = Wq; dh = Wch;          off4 = i4 - 262144; }
    else if (i4 < 393216) { src = Wk; dh = Wch + 262144; off4 = i4 - 327680; }
    else if (i4 < 655360) { src = Wv; dh = Wch + 524288; off4 = i4 - 393216; }
    else                  { src = Wo; dh = Woh;          off4 = i4 - 655360; }
    float4 v = *(const float4*)(src + off4 * 4);
    float vv[4] = {v.x, v.y, v.z, v.w};
    short4v sh;
    #pragma unroll
    for (int e = 0; e < 4; ++e) sh[e] = (short)f2bf_rne(vv[e]);
    *(short4v*)(dh + off4 * 4) = sh;
}

// ---- 2) proj: Cp(bf16) = hs @ Wc^T; 64x96 tile, K-split across 2 wave-halves,
//      512 threads (2 waves/SIMD), BK=64 dbuf per half, LDS reduction epilogue ----
__global__ __launch_bounds__(512)
void gemm_proj(const short* __restrict__ A, const short* __restrict__ Bm,
               short* __restrict__ C) {
    __shared__ short sA[2][2][64][72];   // [half][buf]  36.9 KB
    __shared__ short sB[2][2][96][72];   //              55.3 KB
    __shared__ float sRed[256][24];      //              24.6 KB
    const int tid = threadIdx.x;
    const int half = tid >> 8;           // K-half: 0 or 1
    const int ht = tid & 255;
    const int bm = blockIdx.y * 64, bn = blockIdx.x * 96;
    const int lane = ht & 63, w2 = ht >> 6;
    const int wm = (w2 & 1) * 32, wn = (w2 >> 1) * 48;
    const int srA = ht >> 2, skA = (ht & 3) * 16;
    const int srB = ht >> 1, skB = (ht & 1) * 32;
    const int fm = lane & 15, fk = (lane >> 4) * 8;
    const int kbase = half * 512;
    f32x4 acc[2][3] = {};
    const short* pA = A  + (size_t)(bm + srA) * 1024 + kbase + skA;
    const short* pB = Bm + (size_t)(bn + (srB < 96 ? srB : 0)) * 1024 + kbase + skB;
    bf16x8 va0 = *(const bf16x8*)pA, va1 = *(const bf16x8*)(pA + 8);
    bf16x8 vb0, vb1, vb2, vb3;
    if (ht < 192) {
        vb0 = *(const bf16x8*)pB;        vb1 = *(const bf16x8*)(pB + 8);
        vb2 = *(const bf16x8*)(pB + 16); vb3 = *(const bf16x8*)(pB + 24);
    }
    *(bf16x8*)&sA[half][0][srA][skA]     = va0;
    *(bf16x8*)&sA[half][0][srA][skA + 8] = va1;
    if (ht < 192) {
        *(bf16x8*)&sB[half][0][srB][skB]      = vb0;
        *(bf16x8*)&sB[half][0][srB][skB + 8]  = vb1;
        *(bf16x8*)&sB[half][0][srB][skB + 16] = vb2;
        *(bf16x8*)&sB[half][0][srB][skB + 24] = vb3;
    }
    va0 = *(const bf16x8*)(pA + 64); va1 = *(const bf16x8*)(pA + 72);
    if (ht < 192) {
        vb0 = *(const bf16x8*)(pB + 64); vb1 = *(const bf16x8*)(pB + 72);
        vb2 = *(const bf16x8*)(pB + 80); vb3 = *(const bf16x8*)(pB + 88);
    }
    __syncthreads();
    for (int k0 = 0; k0 < 512; k0 += 64) {
        const int bb = (k0 >> 6) & 1;
        bf16x8 a[2][2], bfr[2][3];
        #pragma unroll
        for (int ks = 0; ks < 2; ++ks) {
            #pragma unroll
            for (int i = 0; i < 2; ++i)
                a[ks][i] = *(const bf16x8*)&sA[half][bb][wm + i*16 + fm][ks*32 + fk];
            #pragma unroll
            for (int j = 0; j < 3; ++j)
                bfr[ks][j] = *(const bf16x8*)&sB[half][bb][wn + j*16 + fm][ks*32 + fk];
        }
        if (k0 + 64 < 512) {
            *(bf16x8*)&sA[half][bb^1][srA][skA]     = va0;
            *(bf16x8*)&sA[half][bb^1][srA][skA + 8] = va1;
            if (ht < 192) {
                *(bf16x8*)&sB[half][bb^1][srB][skB]      = vb0;
                *(bf16x8*)&sB[half][bb^1][srB][skB + 8]  = vb1;
                *(bf16x8*)&sB[half][bb^1][srB][skB + 16] = vb2;
                *(bf16x8*)&sB[half][bb^1][srB][skB + 24] = vb3;
            }
        }
        if (k0 + 128 < 512) {
            va0 = *(const bf16x8*)(pA + k0 + 128); va1 = *(const bf16x8*)(pA + k0 + 136);
            if (ht < 192) {
                vb0 = *(const bf16x8*)(pB + k0 + 128); vb1 = *(const bf16x8*)(pB + k0 + 136);
                vb2 = *(const bf16x8*)(pB + k0 + 144); vb3 = *(const bf16x8*)(pB + k0 + 152);
            }
        }
        #pragma unroll
        for (int ks = 0; ks < 2; ++ks)
            #pragma unroll
            for (int j = 0; j < 3; ++j)
                #pragma unroll
                for (int i = 0; i < 2; ++i)
                    acc[i][j] = mfma1(a[ks][i], bfr[ks][j], acc[i][j]);
        __syncthreads();
    }
    // reduce halves
    __syncthreads();
    if (half == 1) {
        #pragma unroll
        for (int i = 0; i < 2; ++i)
            #pragma unroll
            for (int j = 0; j < 3; ++j)
                *(f32x4*)&sRed[ht][(i*3 + j) * 4] = acc[i][j];
    }
    __syncthreads();
    if (half == 0) {
        const int crow0 = (lane >> 4) * 4, ccol = lane & 15;
        #pragma unroll
        for (int i = 0; i < 2; ++i)
            #pragma unroll
            for (int j = 0; j < 3; ++j) {
                f32x4 o = acc[i][j];
                f32x4 p = *(const f32x4*)&sRed[ht][(i*3 + j) * 4];
                #pragma unroll
                for (int r = 0; r < 4; ++r)
                    C[(size_t)(bm + wm + i*16 + crow0 + r) * 1536 + bn + wn + j*16 + ccol] =
                        (short)f2bf_rne(o[r] + p[r]);
            }
    }
}

// ---- 3) chunk_state: Cp bf16 in (R15 body) ----
__global__ __launch_bounds__(256)
void chunk_state(const short* __restrict__ Cp, short* __restrict__ S, float* __restrict__ Z) {
    const int bh = blockIdx.x >> 3, c = blockIdx.x & 7;
    const int b = bh >> 4, h = bh & 15;
    const int tid = threadIdx.x;
    const int lane = tid & 63, w = tid >> 6;
    const int wm = (w & 1) * 32, wn = (w >> 1) * 80;
    const int fm = lane & 15, fk = (lane >> 4) * 8;
    __shared__ __align__(16) float sKP[64][17];
    __shared__ __align__(16) unsigned short sKT[160][72];
    __shared__ __align__(16) unsigned short sVT[64][72];
    const int r = tid >> 2, q4 = tid & 3;
    const size_t rowbase = (size_t)(b*T + c*CH + r) * 1536;
    {
        short4v kv = *(const short4v*)(Cp + rowbase + 256 + h*16 + q4*4);
        float4 kf;
        kf.x = bf2f((unsigned short)kv[0]); kf.y = bf2f((unsigned short)kv[1]);
        kf.z = bf2f((unsigned short)kv[2]); kf.w = bf2f((unsigned short)kv[3]);
        *(float4*)&sKP[r][q4*4] = kf;
    }
    {
        const short* vsrc = Cp + rowbase + 512 + h*HD + q4*16;
        bf16x8 v0 = *(const bf16x8*)vsrc, v1 = *(const bf16x8*)(vsrc + 8);
        #pragma unroll
        for (int e = 0; e < 8; ++e) {
            sVT[q4*16 + e][r]     = (unsigned short)v0[e];
            sVT[q4*16 + 8 + e][r] = (unsigned short)v1[e];
        }
    }
    __syncthreads();
    feat40T(sKP[r], q4, r, sKT);
    __syncthreads();
    if (tid < DP) {
        float zz = 0.f;
        #pragma unroll
        for (int blk = 0; blk < 8; ++blk) {
            bf16x8 v = *(const bf16x8*)&sKT[tid][blk*8];
            #pragma unroll
            for (int e = 0; e < 8; ++e) zz += bf2f((unsigned short)v[e]);
        }
        Z[((size_t)(bh*NC + c)) * DP + tid] = zz;
    }
    f32x4 acc[2][5] = {};
    #pragma unroll
    for (int k0 = 0; k0 < 64; k0 += 32) {
        bf16x8 a[2];
        #pragma unroll
        for (int i = 0; i < 2; ++i)
            a[i] = *(const bf16x8*)&sVT[wm + i*16 + fm][k0 + fk];
        #pragma unroll
        for (int j = 0; j < 5; ++j) {
            bf16x8 bv = *(const bf16x8*)&sKT[wn + j*16 + fm][k0 + fk];
            #pragma unroll
            for (int i = 0; i < 2; ++i)
                acc[i][j] = mfma1(a[i], bv, acc[i][j]);
        }
    }
    const int crow0 = (lane >> 4) * 4, ccol = lane & 15;
    short* Sb = S + ((size_t)(bh*NC + c)) * CH * DP;
    #pragma unroll
    for (int i = 0; i < 2; ++i)
        #pragma unroll
        for (int j = 0; j < 5; ++j)
            #pragma unroll
            for (int rr = 0; rr < 4; ++rr)
                Sb[(size_t)(wm + i*16 + crow0 + rr) * DP + wn + j*16 + ccol] =
                    (short)f2bf_rne(acc[i][j][rr]);
}

// ---- 4) chunk_out: Cp bf16 in (R15 body) ----
__global__ __launch_bounds__(256)
void chunk_out(const short* __restrict__ Cp, const short* __restrict__ S,
               const float* __restrict__ Z, short* __restrict__ Y) {
    const int bh = blockIdx.x >> 3, c = blockIdx.x & 7;
    const int b = bh >> 4, h = bh & 15;
    const int tid = threadIdx.x;
    const int lane = tid & 63, w = tid >> 6;
    const int wm = (w & 1) * 32, wn = (w >> 1) * 32;
    const int fm = lane & 15, fk = (lane >> 4) * 8;
    __shared__ __align__(16) float sQP[64][17], sKP[64][17];
    __shared__ __align__(16) unsigned short sQf[64][168], sKf[64][168], sPb[64][168];
    __shared__ __align__(16) unsigned short sAb[64][72];
    __shared__ __align__(16) unsigned short sVT[64][72];
    __shared__ float sZp[DP];
    __shared__ float sDen[64];
    const int r = tid >> 2, q4 = tid & 3;
    const size_t rowbase = (size_t)(b*T + c*CH + r) * 1536;
    {
        short4v qv = *(const short4v*)(Cp + rowbase + h*16 + q4*4);
        short4v kv = *(const short4v*)(Cp + rowbase + 256 + h*16 + q4*4);
        float4 qf, kf;
        qf.x = bf2f((unsigned short)qv[0]); qf.y = bf2f((unsigned short)qv[1]);
        qf.z = bf2f((unsigned short)qv[2]); qf.w = bf2f((unsigned short)qv[3]);
        kf.x = bf2f((unsigned short)kv[0]); kf.y = bf2f((unsigned short)kv[1]);
        kf.z = bf2f((unsigned short)kv[2]); kf.w = bf2f((unsigned short)kv[3]);
        *(float4*)&sQP[r][q4*4] = qf;
        *(float4*)&sKP[r][q4*4] = kf;
    }
    {
        const short* vsrc = Cp + rowbase + 512 + h*HD + q4*16;
        bf16x8 v0 = *(const bf16x8*)vsrc, v1 = *(const bf16x8*)(vsrc + 8);
        #pragma unroll
        for (int e = 0; e < 8; ++e) {
            sVT[q4*16 + e][r]     = (unsigned short)v0[e];
            sVT[q4*16 + 8 + e][r] = (unsigned short)v1[e];
        }
    }
    if (tid < DP) {
        float zz = 0.f;
        for (int cc = 0; cc < c; ++cc) zz += Z[((size_t)(bh*NC + cc)) * DP + tid];
        sZp[tid] = zz;
    }
    __syncthreads();
    feat40(sQP[r], q4, (unsigned short*)sQf[r]);
    feat40(sKP[r], q4, (unsigned short*)sKf[r]);
    for (int e = tid; e < 1280; e += 256) {
        const int d = e / 20, D8 = (e % 20) * 8;
        float a[8] = {};
        for (int cc = 0; cc < c; ++cc) {
            bf16x8 s = *(const bf16x8*)(S + (((size_t)(bh*NC + cc)) * CH + d) * DP + D8);
            #pragma unroll
            for (int e2 = 0; e2 < 8; ++e2) a[e2] += bf2f((unsigned short)s[e2]);
        }
        bf16x8 o;
        #pragma unroll
        for (int e2 = 0; e2 < 8; ++e2) o[e2] = (short)f2bf_rne(a[e2]);
        *(bf16x8*)&sPb[d][D8] = o;
    }
    __syncthreads();
    f32x4 accA[2][2] = {};
    f32x4 accI[2][2] = {};
    for (int k0 = 0; k0 < DP; k0 += 32) {
        bf16x8 qv[2];
        #pragma unroll
        for (int i = 0; i < 2; ++i)
            qv[i] = *(const bf16x8*)&sQf[wm + i*16 + fm][k0 + fk];
        #pragma unroll
        for (int j = 0; j < 2; ++j) {
            bf16x8 kv = *(const bf16x8*)&sKf[wn + j*16 + fm][k0 + fk];
            bf16x8 pv = *(const bf16x8*)&sPb[wn + j*16 + fm][k0 + fk];
            #pragma unroll
            for (int i = 0; i < 2; ++i) {
                accA[i][j] = mfma1(qv[i], kv, accA[i][j]);
                accI[i][j] = mfma1(qv[i], pv, accI[i][j]);
            }
        }
    }
    {
        float dp = 0.f;
        #pragma unroll
        for (int g = 0; g < 5; ++g) {
            bf16x8 v = *(const bf16x8*)&sQf[r][q4*40 + g*8];
            #pragma unroll
            for (int e = 0; e < 8; ++e)
                dp += bf2f((unsigned short)v[e]) * sZp[q4*40 + g*8 + e];
        }
        dp += __shfl_xor(dp, 1);
        dp += __shfl_xor(dp, 2);
        if (q4 == 0) sDen[r] = dp;
    }
    const int crow0 = (lane >> 4) * 4, ccol = lane & 15;
    #pragma unroll
    for (int i = 0; i < 2; ++i)
        #pragma unroll
        for (int j = 0; j < 2; ++j)
            #pragma unroll
            for (int rr = 0; rr < 4; ++rr) {
                const int t_ = wm + i*16 + crow0 + rr, s_ = wn + j*16 + ccol;
                sAb[t_][s_] = (s_ <= t_) ? f2bf_rne(accA[i][j][rr]) : 0;
            }
    __syncthreads();
    {
        float rs = 0.f;
        bf16x8 v0 = *(const bf16x8*)&sAb[r][q4*16];
        bf16x8 v1 = *(const bf16x8*)&sAb[r][q4*16 + 8];
        #pragma unroll
        for (int e = 0; e < 8; ++e)
            rs += bf2f((unsigned short)v0[e]) + bf2f((unsigned short)v1[e]);
        rs += __shfl_xor(rs, 1);
        rs += __shfl_xor(rs, 2);
        if (q4 == 0) sDen[r] += rs;
    }
    __syncthreads();
    #pragma unroll
    for (int k0 = 0; k0 < 64; k0 += 32) {
        bf16x8 a[2];
        #pragma unroll
        for (int i = 0; i < 2; ++i)
            a[i] = *(const bf16x8*)&sAb[wm + i*16 + fm][k0 + fk];
        #pragma unroll
        for (int j = 0; j < 2; ++j) {
            bf16x8 bv = *(const bf16x8*)&sVT[wn + j*16 + fm][k0 + fk];
            #pragma unroll
            for (int i = 0; i < 2; ++i)
                accI[i][j] = mfma1(a[i], bv, accI[i][j]);
        }
    }
    #pragma unroll
    for (int i = 0; i < 2; ++i)
        #pragma unroll
        for (int rr = 0; rr < 4; ++rr) {
            const int t_ = wm + i*16 + crow0 + rr;
            const float inv = 1.f / (sDen[t_] + 1e-12f);
            const size_t grow = (size_t)(b*T + c*CH + t_) * 1024 + h*HD;
            #pragma unroll
            for (int j = 0; j < 2; ++j)
                Y[grow + wn + j*16 + ccol] = (short)f2bf_rne(accI[i][j][rr] * inv);
        }
}

// ---- 5) out: out = Y @ Woh^T; 64x64, K-split halves, 512 threads, BK=64 dbuf ----
__global__ __launch_bounds__(512)
void gemm_out(const short* __restrict__ A, const short* __restrict__ Bm,
              float* __restrict__ C) {
    __shared__ short sA[2][2][64][72];   // 36.9 KB
    __shared__ short sB[2][2][64][72];   // 36.9 KB
    __shared__ float sRed[256][16];      // 16.4 KB
    const int tid = threadIdx.x;
    const int half = tid >> 8;
    const int ht = tid & 255;
    const int bm = blockIdx.y * 64, bn = blockIdx.x * 64;
    const int lane = ht & 63, w2 = ht >> 6;
    const int wm = (w2 & 1) * 32, wn = (w2 >> 1) * 32;
    const int srow = ht >> 2, skq = (ht & 3) * 16;
    const int fm = lane & 15, fk = (lane >> 4) * 8;
    const int kbase = half * 512;
    f32x4 acc[2][2] = {};
    const short* pA = A  + (size_t)(bm + srow) * 1024 + kbase + skq;
    const short* pB = Bm + (size_t)(bn + srow) * 1024 + kbase + skq;
    bf16x8 va0 = *(const bf16x8*)pA, va1 = *(const bf16x8*)(pA + 8);
    bf16x8 vb0 = *(const bf16x8*)pB, vb1 = *(const bf16x8*)(pB + 8);
    *(bf16x8*)&sA[half][0][srow][skq]     = va0;
    *(bf16x8*)&sA[half][0][srow][skq + 8] = va1;
    *(bf16x8*)&sB[half][0][srow][skq]     = vb0;
    *(bf16x8*)&sB[half][0][srow][skq + 8] = vb1;
    va0 = *(const bf16x8*)(pA + 64); va1 = *(const bf16x8*)(pA + 72);
    vb0 = *(const bf16x8*)(pB + 64); vb1 = *(const bf16x8*)(pB + 72);
    __syncthreads();
    for (int k0 = 0; k0 < 512; k0 += 64) {
        const int bb = (k0 >> 6) & 1;
        bf16x8 a[2][2], b2[2][2];
        #pragma unroll
        for (int ks = 0; ks < 2; ++ks)
            #pragma unroll
            for (int i = 0; i < 2; ++i) {
                a[ks][i]  = *(const bf16x8*)&sA[half][bb][wm + i*16 + fm][ks*32 + fk];
                b2[ks][i] = *(const bf16x8*)&sB[half][bb][wn + i*16 + fm][ks*32 + fk];
            }
        if (k0 + 64 < 512) {
            *(bf16x8*)&sA[half][bb^1][srow][skq]     = va0;
            *(bf16x8*)&sA[half][bb^1][srow][skq + 8] = va1;
            *(bf16x8*)&sB[half][bb^1][srow][skq]     = vb0;
            *(bf16x8*)&sB[half][bb^1][srow][skq + 8] = vb1;
        }
        if (k0 + 128 < 512) {
            va0 = *(const bf16x8*)(pA + k0 + 128); va1 = *(const bf16x8*)(pA + k0 + 136);
            vb0 = *(const bf16x8*)(pB + k0 + 128); vb1 = *(const bf16x8*)(pB + k0 + 136);
        }
        #pragma unroll
        for (int ks = 0; ks < 2; ++ks)
            #pragma unroll
            for (int i = 0; i < 2; ++i)
                #pragma unroll
                for (int j = 0; j < 2; ++j)
                    acc[i][j] = mfma1(a[ks][i], b2[ks][j], acc[i][j]);
        __syncthreads();
    }
    __syncthreads();
    if (half == 1) {
        #pragma unroll
        for (int i = 0; i < 2; ++i)
            #pragma unroll
            for (int j = 0; j < 2; ++j)
                *(f32x4*)&sRed[ht][(i*2 + j) * 4] = acc[i][j];
    }
    __syncthreads();
    if (half == 0) {
        const int crow0 = (lane >> 4) * 4, ccol = lane & 15;
        #pragma unroll
        for (int i = 0; i < 2; ++i)
            #pragma unroll
            for (int j = 0; j < 2; ++j) {
                f32x4 p = *(const f32x4*)&sRed[ht][(i*2 + j) * 4];
                #pragma unroll
                for (int r = 0; r < 4; ++r)
                    C[(size_t)(bm + wm + i*16 + crow0 + r) * 1024 + bn + wn + j*16 + ccol] =
                        acc[i][j][r] + p[r];
            }
    }
}

extern "C" void kernel_launch(void* const* d_in, const int* in_sizes, int n_in,
                              void* d_out, int out_size, void* d_ws, size_t ws_size,
                              hipStream_t stream) {
    const float* hs = (const float*)d_in[0];
    const float* Wq = (const float*)d_in[1];
    const float* Wk = (const float*)d_in[2];
    const float* Wv = (const float*)d_in[3];
    const float* Wo = (const float*)d_in[4];
    float* out = (float*)d_out;

    char* p = (char*)d_ws;
    short* Cp  = (short*)p; p += (size_t)1024*1536*2;
    short* hsh = (short*)p; p += (size_t)1048576*2;
    short* Wch = (short*)p; p += (size_t)1536*1024*2;
    short* Woh = (short*)p; p += (size_t)1048576*2;
    short* S   = (short*)p; p += (size_t)32*NC*CH*DP*2;
    float* Z   = (float*)p; p += (size_t)32*NC*DP*4;
    short* Y   = (short*)p; p += (size_t)1048576*2;

    preconv<<<dim3(3584), dim3(256), 0, stream>>>(hs, Wq, Wk, Wv, Wo, hsh, Wch, Woh);
    gemm_proj<<<dim3(16, 16), dim3(512), 0, stream>>>(hsh, Wch, Cp);
    chunk_state<<<dim3(256), dim3(256), 0, stream>>>(Cp, S, Z);
    chunk_out<<<dim3(256), dim3(256), 0, stream>>>(Cp, S, Z, Y);
    gemm_out<<<dim3(16, 16), dim3(512), 0, stream>>>(Y, Woh, out);
}